// Round 10
// baseline (156.074 us; speedup 1.0000x reference)
//
#include <hip/hip_runtime.h>
#include <hip/hip_cooperative_groups.h>
#include <hip/hip_bf16.h>
#include <stdint.h>
#include <stddef.h>

// NT-Xent loss, B=4096, D=256, N=8192, T=0.5.
// R17: ONE COOPERATIVE KERNEL (normalize -> grid.sync -> fused symmetric
// ZZ^T sim+exp+sum -> grid.sync -> block-0 finalize/mean). Five structural
// variants of the simexp core (R8/R12/R14/R15/R16) all land 33-36 us and
// are INVISIBLE to rocprof top-5 (below the 43 us harness fills) -> every
// recent round was benched blind. Fusing (a) removes 2 launches + gaps +
// small-kernel overhead (~8-10 us of the 94.3 total) and (b) makes the hot
// loop a ~46 us dispatch = visible in top-5 for a grounded diagnosis.
// Core = R14 verbatim (best measured: 92.08 us): 8 waves in 4x2 (wave =
// 32r x 64c), af[2][8] LDS-bounce-pinned, quadrant phases with deferred
// epilogue slices, 1 __syncthreads/tile, XOR-swizzled LDS (swizzle on
// global source), symmetry (2080 unordered 128x128 tile-pairs), balanced
// tail (s=32 halves on cj2/cj3), exp-scale folded into normalize
// (zn *= sqrt(2/ln2): e = exp2(dot'), pos = dot'*ln2).
// Cooperative launch is sanctioned by the harness (guide §1); grid=256 =
// 1 block/CU (128 KB LDS) -> all blocks co-resident for grid.sync.

#define B_ROWS 4096
#define D_DIM  256
#define N_ROWS 8192
#define BM 128
#define BN 128

namespace cg = cooperative_groups;

typedef __bf16 bf16;
typedef bf16  bf16x8  __attribute__((ext_vector_type(8)));
typedef bf16  bf16x4  __attribute__((ext_vector_type(4)));
typedef float floatx4 __attribute__((ext_vector_type(4)));

__global__ __launch_bounds__(512, 2) void ntxent_fused(
    const float* __restrict__ z_i, const float* __restrict__ z_j,
    bf16* __restrict__ zn, float* __restrict__ sumexp,
    float* __restrict__ pos, float* __restrict__ out) {
  __shared__ __align__(16) bf16 Bs[2][BN * D_DIM];  // 2 x 64 KB

  const int tid   = threadIdx.x;
  const int wave  = tid >> 6;
  const int lane  = tid & 63;

  // ================= phase 0: normalize 32 rows/block ==================
  // row -> L2-normalized bf16 scaled by sqrt(2/ln2); zero sumexp[row].
  #pragma unroll
  for (int rr = 0; rr < 4; ++rr) {
    const int row = blockIdx.x * 32 + wave * 4 + rr;
    const float* src = (row < B_ROWS)
                           ? (z_i + (size_t)row * D_DIM)
                           : (z_j + (size_t)(row - B_ROWS) * D_DIM);
    float4 v = ((const float4*)src)[lane];
    float ss = v.x * v.x + v.y * v.y + v.z * v.z + v.w * v.w;
    #pragma unroll
    for (int m = 1; m < 64; m <<= 1) ss += __shfl_xor(ss, m);
    const float rn = rsqrtf(ss) * 1.6986436f;  // * sqrt(2/ln2)
    bf16x4 o;
    o[0] = (bf16)(v.x * rn);
    o[1] = (bf16)(v.y * rn);
    o[2] = (bf16)(v.z * rn);
    o[3] = (bf16)(v.w * rn);
    ((bf16x4*)(zn + (size_t)row * D_DIM))[lane] = o;
    if (lane == 0) sumexp[row] = 0.f;
  }

  cg::this_grid().sync();  // all zn rows written before any block stages

  // ================= phase 1: sim+exp+sum (R14 core) ===================
  const int lcol  = lane & 15;   // MFMA: A row / B col / C col
  const int lquad = lane >> 4;   // MFMA: k-group / C row-group
  const int wr = (wave >> 1) * 32;  // wave row offset: 0,32,64,96
  const int wc = (wave & 1) * 64;   // wave col offset: 0,64
  const int ri = blockIdx.x >> 2;   // row tile 0..63
  const int cj = blockIdx.x & 3;    // s-chunk 0..3
  const int row_base = ri * BM;
  const bool has_tail = (ri < 32 && cj >= 2);

  auto ct_of = [&](int t) { return (ri + 8 * cj + t) & 63; };

  auto stageB = [&](int buf, const bf16* src, int it0, int it1) {
    for (int it = it0; it < it1; ++it) {
      const int s   = it * 512 + tid;
      const int n   = s >> 5;
      const int kcs = s & 31;
      const int kc  = (kcs & 24) | ((kcs & 7) ^ (n & 7));
      __builtin_amdgcn_global_load_lds(
          (const __attribute__((address_space(1))) unsigned int*)
              (src + (size_t)n * D_DIM + kc * 8),
          (__attribute__((address_space(3))) unsigned int*)&Bs[buf][s * 8],
          16, 0, 0);
    }
  };

  // prologue: A tile -> buf0, first B tile -> buf1, overlapped.
  stageB(0, zn + (size_t)row_base * D_DIM, 0, 8);
  stageB(1, zn + (size_t)ct_of(0) * BM * D_DIM, 0, 8);
  __syncthreads();  // vmcnt(0): both tiles resident

  // af[ti][kq]: buf0 backing overwritten later -> pinned in registers (64).
  floatx4 af[2][8];
  #pragma unroll
  for (int ti = 0; ti < 2; ++ti) {
    const int n = wr + ti * 16 + lcol;
    #pragma unroll
    for (int kq = 0; kq < 8; ++kq) {
      const int kc  = kq * 4 + lquad;
      const int kcs = (kc & 24) | ((kc & 7) ^ (n & 7));
      af[ti][kq] = *(const floatx4*)(&Bs[0][(n * 32 + kcs) * 8]);
    }
  }
  __syncthreads();  // af reads done -> buf0 free for staging

  float rowsum[2][4];  // [ti][r]; row = wr + ti*16 + lquad*4 + r
  #pragma unroll
  for (int ti = 0; ti < 2; ++ti)
    #pragma unroll
    for (int r = 0; r < 4; ++r) rowsum[ti][r] = 0.f;

#define MFMA_(A, B_, C) __builtin_amdgcn_mfma_f32_16x16x32_bf16( \
    __builtin_bit_cast(bf16x8, A), B_, C, 0, 0, 0)

#define QPHASE(ACC, Q)                                                    \
  {                                                                       \
    bf16x8 bfr[8];                                                        \
    const int n = wc + (Q) * 16 + lcol;                                   \
    _Pragma("unroll")                                                     \
    for (int kq = 0; kq < 8; ++kq) {                                      \
      const int kc  = kq * 4 + lquad;                                     \
      const int kcs = (kc & 24) | ((kc & 7) ^ (n & 7));                   \
      bfr[kq] = *(const bf16x8*)(bbase + n * D_DIM + kcs * 8);            \
    }                                                                     \
    ACC[0] = floatx4{0.f, 0.f, 0.f, 0.f};                                 \
    ACC[1] = floatx4{0.f, 0.f, 0.f, 0.f};                                 \
    _Pragma("unroll")                                                     \
    for (int kq = 0; kq < 8; ++kq) {                                      \
      ACC[0] = MFMA_(af[0][kq], bfr[kq], ACC[0]);                         \
      ACC[1] = MFMA_(af[1][kq], bfr[kq], ACC[1]);                         \
    }                                                                     \
  }

#define SLICE(ACC, Q, CB, DG)                                             \
  {                                                                       \
    float cs = 0.f;                                                       \
    _Pragma("unroll")                                                     \
    for (int ti = 0; ti < 2; ++ti) {                                      \
      _Pragma("unroll")                                                   \
      for (int r = 0; r < 4; ++r) {                                       \
        const float v = ACC[ti][r];                                       \
        float e = __builtin_amdgcn_exp2f(v);                              \
        if (DG) {                                                         \
          const int rg = row_base + wr + ti * 16 + lquad * 4 + r;         \
          const int cg = (CB) + wc + (Q) * 16 + lcol;                     \
          if (cg == rg) e = 0.f;  /* mask self-similarity */              \
        }                                                                 \
        rowsum[ti][r] += e;                                               \
        cs += e;                                                          \
      }                                                                   \
    }                                                                     \
    cs += __shfl_xor(cs, 16);                                             \
    cs += __shfl_xor(cs, 32);                                             \
    if (!(DG) && lquad == 0)                                              \
      atomicAdd(&sumexp[(CB) + wc + (Q) * 16 + lcol], cs);                \
  }

  floatx4 a3[2];            // q3 acc, carried one tile (sliced next tile)
  int  pcol3  = 0;
  bool pdiag3 = false;

  #pragma unroll 1
  for (int t = 0; t < 8; ++t) {
    const bf16* bbase = &Bs[(t + 1) & 1][0];   // compute buffer
    const int sb = t & 1;                      // stage buffer (disjoint)
    if (t < 7) {
      stageB(sb, zn + (size_t)ct_of(t + 1) * BM * D_DIM, 0, 8);
    } else if (has_tail) {
      stageB(sb, zn + (size_t)((ri + 32) * BM + (cj - 2) * 64) * D_DIM, 0, 4);
    }
    const int  colb = ct_of(t) * BM;
    const bool diag = (cj == 0 && t == 0);

    floatx4 a0[2], a1[2], a2[2];
    QPHASE(a0, 0)
    if (t > 0) SLICE(a3, 3, pcol3, pdiag3)   // prev tile's q3, overlapped
    QPHASE(a1, 1)
    SLICE(a0, 0, colb, diag)
    QPHASE(a2, 2)
    SLICE(a1, 1, colb, diag)
    QPHASE(a3, 3)
    SLICE(a2, 2, colb, diag)
    pcol3 = colb;
    pdiag3 = diag;
    __syncthreads();  // vmcnt(0)+barrier: stage done, buffer swap safe
  }
  SLICE(a3, 3, pcol3, pdiag3)   // tile 7's q3

  // tail: j64-half (cj-2) of s=32 in buf1; positive pairs live here.
  if (has_tail && wc == 0) {
    const int colb = (ri + 32) * BM + (cj - 2) * 64;
    const bf16* bbase = &Bs[1][0];
    floatx4 ta[2];
    #pragma unroll
    for (int Q = 0; Q < 4; ++Q) {
      QPHASE(ta, Q)
      float cs = 0.f;
      #pragma unroll
      for (int ti = 0; ti < 2; ++ti) {
        #pragma unroll
        for (int r = 0; r < 4; ++r) {
          const float v = ta[ti][r];
          const float e = __builtin_amdgcn_exp2f(v);
          const int rg = row_base + wr + ti * 16 + lquad * 4 + r;
          const int cg = colb + Q * 16 + lcol;
          if (cg == rg + B_ROWS) {                    // positive pair
            const float p = v * 0.6931471805599453f;  // sim/T = v*ln2
            pos[rg] = p;
            pos[cg] = p;
          }
          rowsum[ti][r] += e;
          cs += e;
        }
      }
      cs += __shfl_xor(cs, 16);
      cs += __shfl_xor(cs, 32);
      if (lquad == 0) atomicAdd(&sumexp[colb + Q * 16 + lcol], cs);
    }
  }
#undef SLICE
#undef QPHASE
#undef MFMA_

  // rowsum: reduce 16 col-lanes, 1 atomic per row per wave
  #pragma unroll
  for (int ti = 0; ti < 2; ++ti) {
    #pragma unroll
    for (int r = 0; r < 4; ++r) {
      float s2 = rowsum[ti][r];
      s2 += __shfl_xor(s2, 1);
      s2 += __shfl_xor(s2, 2);
      s2 += __shfl_xor(s2, 4);
      s2 += __shfl_xor(s2, 8);
      if (lcol == 0) {
        const int grow = row_base + wr + ti * 16 + lquad * 4 + r;
        atomicAdd(&sumexp[grow], s2);
      }
    }
  }

  // ================= phase 2: finalize + mean (block 0) ================
  cg::this_grid().sync();  // all sumexp/pos atomics complete
  if (blockIdx.x == 0) {
    float* ws = (float*)&Bs[0][0];  // reuse LDS (block-synced by grid sync)
    const float ln2 = 0.6931471805599453f;
    float s = 0.f;
    #pragma unroll 1
    for (int k = tid; k < N_ROWS; k += 512)
      s += __builtin_amdgcn_logf(sumexp[k]) * ln2 - pos[k];
    #pragma unroll
    for (int m = 1; m < 64; m <<= 1) s += __shfl_xor(s, m);
    if (lane == 0) ws[wave] = s;
    __syncthreads();
    if (wave == 0) {
      float tt = (lane < 8) ? ws[lane] : 0.f;
      #pragma unroll
      for (int m = 1; m < 8; m <<= 1) tt += __shfl_xor(tt, m);
      if (lane == 0) out[0] = tt * (1.0f / N_ROWS);
    }
  }
}

extern "C" void kernel_launch(void* const* d_in, const int* in_sizes, int n_in,
                              void* d_out, int out_size, void* d_ws,
                              size_t ws_size, hipStream_t stream) {
  const float* z_i = (const float*)d_in[0];
  const float* z_j = (const float*)d_in[1];
  float* out = (float*)d_out;

  // workspace layout: zn (4 MB bf16) | sumexp (32 KB) | pos (32 KB)
  bf16* zn = (bf16*)d_ws;
  float* sumexp = (float*)((char*)d_ws + (size_t)N_ROWS * D_DIM * sizeof(bf16));
  float* pos = sumexp + N_ROWS;

  void* args[] = {(void*)&z_i, (void*)&z_j, (void*)&zn,
                  (void*)&sumexp, (void*)&pos, (void*)&out};
  hipLaunchCooperativeKernel((void*)ntxent_fused, dim3(256), dim3(512),
                             args, 0, stream);
}

// Round 11
// 95.485 us; speedup vs baseline: 1.6345x; 1.6345x over previous
//
#include <hip/hip_runtime.h>
#include <hip/hip_bf16.h>
#include <stdint.h>
#include <stddef.h>

// NT-Xent loss, B=4096, D=256, N=8192, T=0.5.
// normalize(+zero sumexp) -> fused symmetric ZZ^T GEMM + exp row/col-sum +
// positive capture -> 1-block finalize/mean. No NxN materialization.
//
// R18: DOUBLE OCCUPANCY (4 waves/SIMD). R17's fused-kernel counters (the
// first ever on our core): MfmaUtil 7.3 + VALUBusy 9.4 => ~83% stall,
// Occupancy 20.6% = the 2-waves/SIMD cap every variant R8-R16 ran at
// (that shared property explains why 5 different schedules all ~33 us).
// VGPR=104 => the 4x2 core fits under 128. Fix: 512-thread blocks with
// BN=64 tiles -> LDS 2x32KB=64KB -> 2 blocks/CU -> 16 waves/CU = 4
// waves/SIMD; __launch_bounds__(512,4) caps VGPR at 128 (budget ~115).
// Epilogue inline: TLP now does the overlap the R13/R14 ILP tricks
// attempted. Grid 64ri x 8cj = 512 = 2/CU exactly.
// (R17 also measured grid.sync cost ~40+ us -> cooperative fusion dead.)
// Carry-overs: A-bounce through LDS (af[2][8]=64 regs pinned; stage A
// halves into both buffers, read, reuse), XOR-swizzled conflict-free LDS
// (swizzle on global source), symmetry (2080 unordered 128x128 tile-pairs:
// row-sums to rows(ri), col-sums to rows(ct), diag s=0 row-only),
// balanced tail (s=32 subtiles on cj6/cj7, <=9 iters), exp-scale folded
// into normalize (zn *= sqrt(2/ln2): e = exp2(dot'), pos = dot'*ln2).

#define B_ROWS 4096
#define D_DIM  256
#define N_ROWS 8192
#define BM 128
#define BN 64

typedef __bf16 bf16;
typedef bf16  bf16x8  __attribute__((ext_vector_type(8)));
typedef bf16  bf16x4  __attribute__((ext_vector_type(4)));
typedef float floatx4 __attribute__((ext_vector_type(4)));

// ---------------------------------------------------------------- normalize
__global__ __launch_bounds__(256) void normalize_kernel(
    const float* __restrict__ z_i, const float* __restrict__ z_j,
    bf16* __restrict__ zn, float* __restrict__ sumexp) {
  const int wave = threadIdx.x >> 6;
  const int lane = threadIdx.x & 63;
  const int row  = blockIdx.x * 4 + wave;
  const float* src = (row < B_ROWS) ? (z_i + (size_t)row * D_DIM)
                                    : (z_j + (size_t)(row - B_ROWS) * D_DIM);
  float4 v = ((const float4*)src)[lane];
  float ss = v.x * v.x + v.y * v.y + v.z * v.z + v.w * v.w;
  #pragma unroll
  for (int m = 1; m < 64; m <<= 1) ss += __shfl_xor(ss, m);
  const float rn = rsqrtf(ss) * 1.6986436f;  // * sqrt(2/ln2)
  bf16x4 o;
  o[0] = (bf16)(v.x * rn);
  o[1] = (bf16)(v.y * rn);
  o[2] = (bf16)(v.z * rn);
  o[3] = (bf16)(v.w * rn);
  ((bf16x4*)(zn + (size_t)row * D_DIM))[lane] = o;
  if (lane == 0) sumexp[row] = 0.f;
}

// ------------------------------------------------------- fused sim+exp+sum
// Grid: 64 ri x 8 cj = 512 blocks (2/CU by 64 KB LDS + 128-VGPR cap).
// Block (ri,cj): j64-tiles s = 4cj+p (p=0..3), two 64-col subtiles each;
// (ri<32, cj==6) adds subtile 0 of s=32, (cj==7) subtile 1 -> 8 or 9
// iterations. 8 waves in 4x2 (wave = 32 rows x 32 cols); per j64-tile the
// wave does 2 col-quadrants of {8 ds_read_b128 + 16 MFMA + inline slice}.
__global__ __launch_bounds__(512, 4) void simexp_kernel(
    const bf16* __restrict__ zn, float* __restrict__ sumexp,
    float* __restrict__ pos) {
  __shared__ __align__(16) bf16 Bs[2][BN * D_DIM];  // 2 x 32 KB

  const int tid   = threadIdx.x;
  const int wave  = tid >> 6;
  const int lane  = tid & 63;
  const int lcol  = lane & 15;   // MFMA: A row / B col / C col
  const int lquad = lane >> 4;   // MFMA: k-group / C row-group
  const int wr = (wave >> 1) * 32;  // wave row offset: 0,32,64,96
  const int wc = (wave & 1) * 32;   // wave col offset: 0,32
  const int ri = blockIdx.x >> 3;   // row tile 0..63
  const int cj = blockIdx.x & 7;    // s-chunk 0..7
  const int row_base = ri * BM;
  const int niter = (ri < 32 && cj >= 6) ? 9 : 8;

  // iteration -> j64-tile index (0..127)
  auto jt64 = [&](int t) {
    const int s   = (t == 8) ? 32 : 4 * cj + (t >> 1);
    const int sub = (t == 8) ? (cj - 6) : (t & 1);
    return 2 * ((ri + s) & 63) + sub;
  };

  // stage a 64-row x 256-k tile (32 KB): 4 x 16B per thread, coalesced,
  // swizzle applied on the GLOBAL source address (LDS dest linear).
  auto stageB = [&](int buf, const bf16* src) {
    #pragma unroll
    for (int it = 0; it < 4; ++it) {
      const int s   = it * 512 + tid;
      const int n   = s >> 5;           // row 0..63
      const int kcs = s & 31;           // swizzled k-chunk slot
      const int kc  = (kcs & 24) | ((kcs & 7) ^ (n & 7));
      __builtin_amdgcn_global_load_lds(
          (const __attribute__((address_space(1))) unsigned int*)
              (src + (size_t)n * D_DIM + kc * 8),
          (__attribute__((address_space(3))) unsigned int*)&Bs[buf][s * 8],
          16, 0, 0);
    }
  };

  // ---- prologue: A halves -> buf0,buf1; read af; then reuse buffers.
  stageB(0, zn + (size_t)row_base * D_DIM);          // A rows 0..63
  stageB(1, zn + (size_t)(row_base + 64) * D_DIM);   // A rows 64..127
  __syncthreads();  // vmcnt(0): A resident

  // af[ti][kq]: row = row_base+wr+ti*16+lcol; backing overwritten later
  // -> pinned in registers (64 VGPRs).
  floatx4 af[2][8];
  #pragma unroll
  for (int ti = 0; ti < 2; ++ti) {
    const int n    = wr + ti * 16 + lcol;   // 0..127
    const int half = n >> 6;
    const int nl   = n & 63;
    #pragma unroll
    for (int kq = 0; kq < 8; ++kq) {
      const int kc  = kq * 4 + lquad;
      const int kcs = (kc & 24) | ((kc & 7) ^ (nl & 7));
      af[ti][kq] = *(const floatx4*)(&Bs[half][(nl * 32 + kcs) * 8]);
    }
  }
  __syncthreads();  // af reads done -> buffers free for B staging

  stageB(0, zn + (size_t)jt64(0) * BN * D_DIM);  // first B prefetch

  float rowsum[2][4];  // [ti][r]; row = wr + ti*16 + lquad*4 + r
  #pragma unroll
  for (int ti = 0; ti < 2; ++ti)
    #pragma unroll
    for (int r = 0; r < 4; ++r) rowsum[ti][r] = 0.f;

#define MFMA_(A, B_, C) __builtin_amdgcn_mfma_f32_16x16x32_bf16( \
    __builtin_bit_cast(bf16x8, A), B_, C, 0, 0, 0)

  #pragma unroll 1  // one body copy (I$); single barrier per tile
  for (int t = 0; t < niter; ++t) {
    __syncthreads();  // drains prefetch for buf[t&1]; fences other-buf
    if (t + 1 < niter) stageB((t + 1) & 1, zn + (size_t)jt64(t + 1) * BN * D_DIM);

    const bf16* bbase = &Bs[t & 1][0];
    const int s    = (t == 8) ? 32 : 4 * cj + (t >> 1);
    const bool diag = (s == 0);
    const bool posT = (s == 32);
    const int colb = jt64(t) * BN;

    // two 16-col quadrants; epilogue inline (TLP hides it at 4 waves/SIMD)
    #pragma unroll
    for (int Q = 0; Q < 2; ++Q) {
      const int n = wc + Q * 16 + lcol;   // B col 0..63
      floatx4 acc[2];
      acc[0] = floatx4{0.f, 0.f, 0.f, 0.f};
      acc[1] = floatx4{0.f, 0.f, 0.f, 0.f};
      #pragma unroll
      for (int kq = 0; kq < 8; ++kq) {
        const int kc  = kq * 4 + lquad;
        const int kcs = (kc & 24) | ((kc & 7) ^ (n & 7));
        const bf16x8 b = *(const bf16x8*)(bbase + n * D_DIM + kcs * 8);
        acc[0] = MFMA_(af[0][kq], b, acc[0]);
        acc[1] = MFMA_(af[1][kq], b, acc[1]);
      }
      // slice: e = exp(sim/T) = 2^v (scale pre-folded into zn)
      float cs = 0.f;
      #pragma unroll
      for (int ti = 0; ti < 2; ++ti) {
        #pragma unroll
        for (int r = 0; r < 4; ++r) {
          const float v = acc[ti][r];
          float e = __builtin_amdgcn_exp2f(v);
          if (diag || posT) {
            const int rg = row_base + wr + ti * 16 + lquad * 4 + r;
            const int cg = colb + wc + Q * 16 + lcol;
            if (diag && cg == rg) e = 0.f;               // mask self
            if (posT && cg == rg + B_ROWS) {             // positive pair
              const float p = v * 0.6931471805599453f;   // sim/T = v*ln2
              pos[rg] = p;
              pos[cg] = p;
            }
          }
          rowsum[ti][r] += e;
          cs += e;
        }
      }
      cs += __shfl_xor(cs, 16);
      cs += __shfl_xor(cs, 32);
      if (!diag && lquad == 0)
        atomicAdd(&sumexp[colb + wc + Q * 16 + lcol], cs);
    }
  }
#undef MFMA_

  // rowsum: reduce 16 col-lanes, 1 atomic per row per wave
  #pragma unroll
  for (int ti = 0; ti < 2; ++ti) {
    #pragma unroll
    for (int r = 0; r < 4; ++r) {
      float s2 = rowsum[ti][r];
      s2 += __shfl_xor(s2, 1);
      s2 += __shfl_xor(s2, 2);
      s2 += __shfl_xor(s2, 4);
      s2 += __shfl_xor(s2, 8);
      if (lcol == 0) {
        const int grow = row_base + wr + ti * 16 + lquad * 4 + r;
        atomicAdd(&sumexp[grow], s2);
      }
    }
  }
}

// ------------------------------------------------- finalize + mean (1 block)
__global__ __launch_bounds__(1024) void reduce_kernel(
    const float* __restrict__ sumexp, const float* __restrict__ pos,
    float* __restrict__ out) {
  __shared__ float ws[16];
  const int tid = threadIdx.x;
  float s = 0.f;
  const float ln2 = 0.6931471805599453f;
  for (int k = tid; k < N_ROWS; k += 1024)
    s += __builtin_amdgcn_logf(sumexp[k]) * ln2 - pos[k];
  #pragma unroll
  for (int m = 1; m < 64; m <<= 1) s += __shfl_xor(s, m);
  const int wave = tid >> 6, lane = tid & 63;
  if (lane == 0) ws[wave] = s;
  __syncthreads();
  if (wave == 0) {
    float t = (lane < 16) ? ws[lane] : 0.f;
    #pragma unroll
    for (int m = 1; m < 16; m <<= 1) t += __shfl_xor(t, m);
    if (lane == 0) out[0] = t * (1.0f / N_ROWS);
  }
}

extern "C" void kernel_launch(void* const* d_in, const int* in_sizes, int n_in,
                              void* d_out, int out_size, void* d_ws,
                              size_t ws_size, hipStream_t stream) {
  const float* z_i = (const float*)d_in[0];
  const float* z_j = (const float*)d_in[1];
  float* out = (float*)d_out;

  // workspace layout: zn (4 MB bf16) | sumexp (32 KB) | pos (32 KB)
  bf16* zn = (bf16*)d_ws;
  float* sumexp = (float*)((char*)d_ws + (size_t)N_ROWS * D_DIM * sizeof(bf16));
  float* pos = sumexp + N_ROWS;

  normalize_kernel<<<N_ROWS / 4, 256, 0, stream>>>(z_i, z_j, zn, sumexp);
  simexp_kernel<<<512, 512, 0, stream>>>(zn, sumexp, pos);
  reduce_kernel<<<1, 1024, 0, stream>>>(sumexp, pos, out);
}

// Round 14
// 90.021 us; speedup vs baseline: 1.7338x; 1.0607x over previous
//
#include <hip/hip_runtime.h>
#include <hip/hip_bf16.h>
#include <stdint.h>
#include <stddef.h>

// NT-Xent loss, B=4096, D=256, N=8192, T=0.5.
// normalize(+zero sumexp/out) -> fused symmetric ZZ^T GEMM + exp
// row/col-sum + positive capture -> 32-block finalize/mean. No NxN.
//
// R19 (2nd resubmit; R12+R13 benches were GPUAcquisitionTimeouts, no
// data): OVERHEAD HARVEST; CORE FROZEN AT R14 (proven best, 92.08 us).
// Seven core variants (R8/R12/R14/R15/R16/R18: barriers, vmcnt policy,
// LDS-read volume, occupancy 2->4 waves/SIMD) all land ~33-36 us => the
// core behaves pipe-SUM-serial (MFMA 2.5k + LDS 3.1k + L2-stage 2.3k +
// VALU/trans 1.6k ~ 9.5k cyc/tile = measured); stop re-rolling. This
// round removes attributable NON-core time:
//  (a) reduce was 1 block = 1 CU doing 8192 logs on one trans pipe
//      (~7 us) -> 32 blocks x 256 thr, 1 row/thread, block partial ->
//      atomicAdd(out) (~1.5 us). out zeroed in normalize (stream-ordered).
//  (b) simexp prologue: af reads only need the A tile -> vmcnt(8)+barrier
//      (B0's 8 loads stay in flight) instead of full __syncthreads drain.
// Core carry-overs (R14): 8 waves in 4x2 (wave = 32r x 64c), af[2][8]
// LDS-bounce-pinned, quadrant phases with deferred epilogue slices
// (q3 carried one tile), 1 __syncthreads/tile, XOR-swizzled LDS (swizzle
// on global source), symmetry (2080 unordered 128x128 tile-pairs:
// row-sums to rows(ri), col-sums to rows(ct), diag s=0 row-only),
// balanced tail (s=32 halves on cj2/cj3), exp-scale folded into
// normalize (zn *= sqrt(2/ln2): e = exp2(dot'), pos = dot'*ln2).

#define B_ROWS 4096
#define D_DIM  256
#define N_ROWS 8192
#define BM 128
#define BN 128

typedef __bf16 bf16;
typedef bf16  bf16x8  __attribute__((ext_vector_type(8)));
typedef bf16  bf16x4  __attribute__((ext_vector_type(4)));
typedef float floatx4 __attribute__((ext_vector_type(4)));

// ---------------------------------------------------------------- normalize
// One wave per row: 256 fp32 -> L2-normalized bf16 scaled by sqrt(2/ln2)
// so dot' = (2/ln2)*dot and e = exp2(dot'). Zeroes sumexp; zeroes out[0].
__global__ __launch_bounds__(256) void normalize_kernel(
    const float* __restrict__ z_i, const float* __restrict__ z_j,
    bf16* __restrict__ zn, float* __restrict__ sumexp,
    float* __restrict__ out) {
  const int wave = threadIdx.x >> 6;
  const int lane = threadIdx.x & 63;
  const int row  = blockIdx.x * 4 + wave;
  if (blockIdx.x == 0 && threadIdx.x == 0) out[0] = 0.f;
  const float* src = (row < B_ROWS) ? (z_i + (size_t)row * D_DIM)
                                    : (z_j + (size_t)(row - B_ROWS) * D_DIM);
  float4 v = ((const float4*)src)[lane];
  float ss = v.x * v.x + v.y * v.y + v.z * v.z + v.w * v.w;
  #pragma unroll
  for (int m = 1; m < 64; m <<= 1) ss += __shfl_xor(ss, m);
  const float rn = rsqrtf(ss) * 1.6986436f;  // * sqrt(2/ln2)
  bf16x4 o;
  o[0] = (bf16)(v.x * rn);
  o[1] = (bf16)(v.y * rn);
  o[2] = (bf16)(v.z * rn);
  o[3] = (bf16)(v.w * rn);
  ((bf16x4*)(zn + (size_t)row * D_DIM))[lane] = o;
  if (lane == 0) sumexp[row] = 0.f;
}

// ------------------------------------------------------- fused sim+exp+sum
// Grid: 64 ri x 4 cj = 256 blocks (1/CU by 128 KB LDS). Block (ri,cj): 8
// tiles s=8cj+t; (ri<32, cj>=2) add the j64-half (cj-2) of s=32 (tail).
// 8 waves in 4x2 (wave = 32 rows x 64 cols); quadrant phases (16 cols x
// full K = 16 MFMA), finished quadrant's exp/sum slice overlaps the next
// quadrant's MFMAs; q3 carried one tile. LDS XOR-swizzled (swizzle on the
// GLOBAL source address; LDS dest linear).
__global__ __launch_bounds__(512, 2) void simexp_kernel(
    const bf16* __restrict__ zn, float* __restrict__ sumexp,
    float* __restrict__ pos) {
  __shared__ __align__(16) bf16 Bs[2][BN * D_DIM];  // 2 x 64 KB

  const int tid   = threadIdx.x;
  const int wave  = tid >> 6;
  const int lane  = tid & 63;
  const int lcol  = lane & 15;   // MFMA: A row / B col / C col
  const int lquad = lane >> 4;   // MFMA: k-group / C row-group
  const int wr = (wave >> 1) * 32;  // wave row offset: 0,32,64,96
  const int wc = (wave & 1) * 64;   // wave col offset: 0,64
  const int ri = blockIdx.x >> 2;   // row tile 0..63
  const int cj = blockIdx.x & 3;    // s-chunk 0..3
  const int row_base = ri * BM;
  const bool has_tail = (ri < 32 && cj >= 2);

  auto ct_of = [&](int t) { return (ri + 8 * cj + t) & 63; };  // col tile

  // stage rows of a tile into Bs[buf]: chunk slot s=it*512+tid, row n=s>>5,
  // swizzled k-chunk; coalesced 16B global_load_lds, source pre-swizzled.
  auto stageB = [&](int buf, const bf16* src, int it0, int it1) {
    for (int it = it0; it < it1; ++it) {
      const int s   = it * 512 + tid;
      const int n   = s >> 5;
      const int kcs = s & 31;
      const int kc  = (kcs & 24) | ((kcs & 7) ^ (n & 7));
      __builtin_amdgcn_global_load_lds(
          (const __attribute__((address_space(1))) unsigned int*)
              (src + (size_t)n * D_DIM + kc * 8),
          (__attribute__((address_space(3))) unsigned int*)&Bs[buf][s * 8],
          16, 0, 0);
    }
  };

  // ---- prologue: A tile -> buf0, first B tile -> buf1, overlapped.
  stageB(0, zn + (size_t)row_base * D_DIM, 0, 8);
  stageB(1, zn + (size_t)ct_of(0) * BM * D_DIM, 0, 8);
  // af reads only need A: wait A's 8 loads (B0's 8 still in flight).
  asm volatile("s_waitcnt vmcnt(8)" ::: "memory");
  __builtin_amdgcn_sched_barrier(0);
  __builtin_amdgcn_s_barrier();

  // af[ti][kq]: buf0 backing overwritten later -> pinned in registers (64).
  floatx4 af[2][8];
  #pragma unroll
  for (int ti = 0; ti < 2; ++ti) {
    const int n = wr + ti * 16 + lcol;
    #pragma unroll
    for (int kq = 0; kq < 8; ++kq) {
      const int kc  = kq * 4 + lquad;
      const int kcs = (kc & 24) | ((kc & 7) ^ (n & 7));
      af[ti][kq] = *(const floatx4*)(&Bs[0][(n * 32 + kcs) * 8]);
    }
  }
  __syncthreads();  // drains B0 + af reads -> buf0 free for staging

  float rowsum[2][4];  // [ti][r]; row = wr + ti*16 + lquad*4 + r
  #pragma unroll
  for (int ti = 0; ti < 2; ++ti)
    #pragma unroll
    for (int r = 0; r < 4; ++r) rowsum[ti][r] = 0.f;

#define MFMA_(A, B_, C) __builtin_amdgcn_mfma_f32_16x16x32_bf16( \
    __builtin_bit_cast(bf16x8, A), B_, C, 0, 0, 0)

#define QPHASE(ACC, Q)                                                    \
  {                                                                       \
    bf16x8 bfr[8];                                                        \
    const int n = wc + (Q) * 16 + lcol;                                   \
    _Pragma("unroll")                                                     \
    for (int kq = 0; kq < 8; ++kq) {                                      \
      const int kc  = kq * 4 + lquad;                                     \
      const int kcs = (kc & 24) | ((kc & 7) ^ (n & 7));                   \
      bfr[kq] = *(const bf16x8*)(bbase + n * D_DIM + kcs * 8);            \
    }                                                                     \
    ACC[0] = floatx4{0.f, 0.f, 0.f, 0.f};                                 \
    ACC[1] = floatx4{0.f, 0.f, 0.f, 0.f};                                 \
    _Pragma("unroll")                                                     \
    for (int kq = 0; kq < 8; ++kq) {                                      \
      ACC[0] = MFMA_(af[0][kq], bfr[kq], ACC[0]);                         \
      ACC[1] = MFMA_(af[1][kq], bfr[kq], ACC[1]);                         \
    }                                                                     \
  }

#define SLICE(ACC, Q, CB, DG)                                             \
  {                                                                       \
    float cs = 0.f;                                                       \
    _Pragma("unroll")                                                     \
    for (int ti = 0; ti < 2; ++ti) {                                      \
      _Pragma("unroll")                                                   \
      for (int r = 0; r < 4; ++r) {                                       \
        const float v = ACC[ti][r];                                       \
        float e = __builtin_amdgcn_exp2f(v);                              \
        if (DG) {                                                         \
          const int rg = row_base + wr + ti * 16 + lquad * 4 + r;         \
          const int cg = (CB) + wc + (Q) * 16 + lcol;                     \
          if (cg == rg) e = 0.f;  /* mask self-similarity */              \
        }                                                                 \
        rowsum[ti][r] += e;                                               \
        cs += e;                                                          \
      }                                                                   \
    }                                                                     \
    cs += __shfl_xor(cs, 16);                                             \
    cs += __shfl_xor(cs, 32);                                             \
    if (!(DG) && lquad == 0)                                              \
      atomicAdd(&sumexp[(CB) + wc + (Q) * 16 + lcol], cs);                \
  }

  floatx4 a3[2];            // q3 acc, carried one tile (sliced next tile)
  int  pcol3  = 0;
  bool pdiag3 = false;

  #pragma unroll 1
  for (int t = 0; t < 8; ++t) {
    const bf16* bbase = &Bs[(t + 1) & 1][0];   // compute buffer
    const int sb = t & 1;                      // stage buffer (disjoint)
    if (t < 7) {
      stageB(sb, zn + (size_t)ct_of(t + 1) * BM * D_DIM, 0, 8);
    } else if (has_tail) {
      stageB(sb, zn + (size_t)((ri + 32) * BM + (cj - 2) * 64) * D_DIM, 0, 4);
    }
    const int  colb = ct_of(t) * BM;
    const bool diag = (cj == 0 && t == 0);

    floatx4 a0[2], a1[2], a2[2];
    QPHASE(a0, 0)
    if (t > 0) SLICE(a3, 3, pcol3, pdiag3)   // prev tile's q3, overlapped
    QPHASE(a1, 1)
    SLICE(a0, 0, colb, diag)
    QPHASE(a2, 2)
    SLICE(a1, 1, colb, diag)
    QPHASE(a3, 3)
    SLICE(a2, 2, colb, diag)
    pcol3 = colb;
    pdiag3 = diag;
    __syncthreads();  // vmcnt(0)+barrier: stage done, buffer swap safe
  }
  SLICE(a3, 3, pcol3, pdiag3)   // tile 7's q3

  // tail: j64-half (cj-2) of s=32 in buf1; positive pairs live here.
  if (has_tail && wc == 0) {
    const int colb = (ri + 32) * BM + (cj - 2) * 64;
    const bf16* bbase = &Bs[1][0];
    floatx4 ta[2];
    #pragma unroll
    for (int Q = 0; Q < 4; ++Q) {
      QPHASE(ta, Q)
      float cs = 0.f;
      #pragma unroll
      for (int ti = 0; ti < 2; ++ti) {
        #pragma unroll
        for (int r = 0; r < 4; ++r) {
          const float v = ta[ti][r];
          const float e = __builtin_amdgcn_exp2f(v);
          const int rg = row_base + wr + ti * 16 + lquad * 4 + r;
          const int cg = colb + Q * 16 + lcol;
          if (cg == rg + B_ROWS) {                    // positive pair
            const float p = v * 0.6931471805599453f;  // sim/T = v*ln2
            pos[rg] = p;
            pos[cg] = p;
          }
          rowsum[ti][r] += e;
          cs += e;
        }
      }
      cs += __shfl_xor(cs, 16);
      cs += __shfl_xor(cs, 32);
      if (lquad == 0) atomicAdd(&sumexp[colb + Q * 16 + lcol], cs);
    }
  }
#undef SLICE
#undef QPHASE
#undef MFMA_

  // rowsum: reduce 16 col-lanes, 1 atomic per row per wave
  #pragma unroll
  for (int ti = 0; ti < 2; ++ti) {
    #pragma unroll
    for (int r = 0; r < 4; ++r) {
      float s2 = rowsum[ti][r];
      s2 += __shfl_xor(s2, 1);
      s2 += __shfl_xor(s2, 2);
      s2 += __shfl_xor(s2, 4);
      s2 += __shfl_xor(s2, 8);
      if (lcol == 0) {
        const int grow = row_base + wr + ti * 16 + lquad * 4 + r;
        atomicAdd(&sumexp[grow], s2);
      }
    }
  }
}

// ------------------------------------------- finalize + mean (32 blocks)
// loss_k = log(sumexp_k) - pos_k ; out += block_partial / N.
// 32 blocks x 256 threads = 8192 threads, one row each -> log work spread
// across 32 CUs (was 1 block = 1 CU = ~7 us of serialized trans ops).
__global__ __launch_bounds__(256) void reduce_kernel(
    const float* __restrict__ sumexp, const float* __restrict__ pos,
    float* __restrict__ out) {
  __shared__ float ws[4];
  const int tid = threadIdx.x;
  const int k = blockIdx.x * 256 + tid;
  const float ln2 = 0.6931471805599453f;
  float s = __builtin_amdgcn_logf(sumexp[k]) * ln2 - pos[k];
  #pragma unroll
  for (int m = 1; m < 64; m <<= 1) s += __shfl_xor(s, m);
  const int wave = tid >> 6, lane = tid & 63;
  if (lane == 0) ws[wave] = s;
  __syncthreads();
  if (tid == 0) {
    const float t = ws[0] + ws[1] + ws[2] + ws[3];
    atomicAdd(out, t * (1.0f / N_ROWS));
  }
}

extern "C" void kernel_launch(void* const* d_in, const int* in_sizes, int n_in,
                              void* d_out, int out_size, void* d_ws,
                              size_t ws_size, hipStream_t stream) {
  const float* z_i = (const float*)d_in[0];
  const float* z_j = (const float*)d_in[1];
  float* out = (float*)d_out;

  // workspace layout: zn (4 MB bf16) | sumexp (32 KB) | pos (32 KB)
  bf16* zn = (bf16*)d_ws;
  float* sumexp = (float*)((char*)d_ws + (size_t)N_ROWS * D_DIM * sizeof(bf16));
  float* pos = sumexp + N_ROWS;

  normalize_kernel<<<N_ROWS / 4, 256, 0, stream>>>(z_i, z_j, zn, sumexp, out);
  simexp_kernel<<<256, 512, 0, stream>>>(zn, sumexp, pos);
  reduce_kernel<<<32, 256, 0, stream>>>(sumexp, pos, out);
}